// Round 4
// baseline (89.991 us; speedup 1.0000x reference)
//
#include <hip/hip_runtime.h>

// Problem constants (match reference setup_inputs)
#define K_SIZE 5
#define PAD 2
#define SAMPLE_NUM 15
#define DEPTH_MAX 192.0f

constexpr int B = 2, C = 32, H = 240, W = 320;
constexpr int HW = H * W;
constexpr int PPB = 64;            // pixels per block
constexpr int NG = 4, CPG = 8;     // channel groups x channels per group
constexpr int NBLK = (B * HW) / PPB;  // 2400

__global__ __launch_bounds__(256, 6) void adaptive_sample_kernel(
    const float* __restrict__ depth,      // [B,1,H,W]
    const float* __restrict__ sn,         // [B,3,H,W]
    const float* __restrict__ features,   // [B,C,H,W]
    const float* __restrict__ guide,      // [B,H,W,25]
    const int*   __restrict__ sample_idx, // [15]
    float* __restrict__ out,              // [B,C,H,W]
    float* __restrict__ feat_out)         // [B,C,H,W]
{
    // [s][p] layout: phase-1 writes and phase-2 reads have lanes = consecutive
    // pixels p -> consecutive addresses -> conflict-free LDS.
    __shared__ float w_lds[SAMPLE_NUM][PPB];
    __shared__ int   o_lds[SAMPLE_NUM][PPB];

    const int tid = threadIdx.x;
    const int p   = tid & (PPB - 1);   // pixel within block
    const int sub = tid >> 6;          // wave id: sample-subset (ph1) / channel-group (ph2)
    const int n   = blockIdx.x * PPB + p;
    const int b   = n / HW;
    const int pix = n - b * HW;
    const int y   = pix / W;
    const int x   = pix - y * W;

    const float* snb = sn + (size_t)b * 3 * HW;
    const float* db  = depth + (size_t)b * HW;

    // ---- phase 1: cooperative weight computation (<=4 samples per thread) ----
    {
        // center_n per reference: RAW RESHAPE of [B,3,H,W] -> (B,H,W,3)
        int o = y * (W * 3) + x * 3;
        float cn0 = snb[o], cn1 = snb[o + 1], cn2 = snb[o + 2];
        const float* gb = guide + ((size_t)b * HW + pix) * (K_SIZE * K_SIZE);
        #pragma unroll
        for (int k = 0; k < 4; ++k) {
            int s = sub * 4 + k;                 // 0..15; s==15 skipped
            if (s < SAMPLE_NUM) {
                int pp = sample_idx[s];          // wave-uniform
                int dy = pp / K_SIZE - PAD;
                int dx = pp - (pp / K_SIZE) * K_SIZE - PAD;
                int yy = y + dy, xx = x + dx;
                bool inb = (yy >= 0) && (yy < H) && (xx >= 0) && (xx < W);
                int noff = inb ? (yy * W + xx) : pix;   // clamped; weight zeroed later
                float ww = -1.0f;                        // negative marks OOB
                if (inb) {
                    ww = 0.0f;
                    float d = db[noff];
                    if (d > 0.0f && d < DEPTH_MAX) {
                        float d0 = snb[noff]          - cn0;
                        float d1 = snb[HW + noff]     - cn1;
                        float d2 = snb[2 * HW + noff] - cn2;
                        float diff = sqrtf(d0 * d0 + d1 * d1 + d2 * d2);
                        ww = __expf(-0.5f * diff) * gb[pp];
                    }
                }
                w_lds[s][p] = ww;
                o_lds[s][p] = noff;
            }
        }
    }
    __syncthreads();

    // ---- phase 1.5: one lane per pixel: softmax over 15, write accum weights ----
    if (tid < PPB) {
        float v[SAMPLE_NUM];
        float m = 0.0f;   // pre-softmax weights are >= 0 (OOB counts as 0)
        #pragma unroll
        for (int s = 0; s < SAMPLE_NUM; ++s) { v[s] = w_lds[s][tid]; m = fmaxf(m, v[s]); }
        float e[SAMPLE_NUM];
        float sum = 0.0f;
        #pragma unroll
        for (int s = 0; s < SAMPLE_NUM; ++s) {
            float pre = fmaxf(v[s], 0.0f);       // OOB (-1) -> pre-softmax 0
            e[s] = __expf(pre - m);
            sum += e[s];
        }
        float inv = 1.0f / sum;
        #pragma unroll
        for (int s = 0; s < SAMPLE_NUM; ++s)
            w_lds[s][tid] = (v[s] < 0.0f) ? 0.0f : e[s] * inv;  // OOB feature is 0 (zero pad)
    }
    __syncthreads();

    // ---- phase 2: each thread accumulates 8 channels for its pixel ----
    float wv[SAMPLE_NUM];
    int   ov[SAMPLE_NUM];
    #pragma unroll
    for (int s = 0; s < SAMPLE_NUM; ++s) { wv[s] = w_lds[s][p]; ov[s] = o_lds[s][p]; }

    const float* fb  = features + (size_t)b * C * HW;
    float*       ob  = out      + (size_t)b * C * HW;
    float*       fob = feat_out + (size_t)b * C * HW;
    const int c0 = sub * CPG;

    float acc[CPG];
    #pragma unroll
    for (int cc = 0; cc < CPG; ++cc) acc[cc] = 0.0f;

    #pragma unroll
    for (int s = 0; s < SAMPLE_NUM; ++s) {
        const float* fo = fb + ov[s];
        float wgt = wv[s];
        #pragma unroll
        for (int cc = 0; cc < CPG; ++cc)
            acc[cc] = fmaf(wgt, fo[(size_t)(c0 + cc) * HW], acc[cc]);
    }

    #pragma unroll
    for (int cc = 0; cc < CPG; ++cc) {
        size_t idx = (size_t)(c0 + cc) * HW + pix;
        ob[idx]  = acc[cc];     // weighted sample output
        fob[idx] = fb[idx];     // features passthrough (output 1)
    }
}

extern "C" void kernel_launch(void* const* d_in, const int* in_sizes, int n_in,
                              void* d_out, int out_size, void* d_ws, size_t ws_size,
                              hipStream_t stream) {
    const float* depth      = (const float*)d_in[0];
    const float* sn         = (const float*)d_in[1];
    const float* features   = (const float*)d_in[2];
    const float* guide      = (const float*)d_in[3];
    const int*   sample_idx = (const int*)d_in[4];

    float* out      = (float*)d_out;                      // [B,C,H,W]
    float* feat_out = (float*)d_out + (size_t)B * C * HW; // [B,C,H,W]

    adaptive_sample_kernel<<<NBLK, 256, 0, stream>>>(
        depth, sn, features, guide, sample_idx, out, feat_out);
}

// Round 5
// 42.120 us; speedup vs baseline: 2.1365x; 2.1365x over previous
//
#include <hip/hip_runtime.h>

// Problem constants (match reference setup_inputs)
#define K_SIZE 5
#define PAD 2
#define SAMPLE_NUM 15
#define DEPTH_MAX 192.0f

constexpr int B = 2, C = 32, H = 240, W = 320;
constexpr int HW = H * W;
constexpr int BHW = B * HW;          // 153600
constexpr size_t WS_NEED = (size_t)BHW * 16 * sizeof(float);  // 9.83 MB

// ---------------- Kernel A: pre-softmax weights, one thread per (pixel, sample) ----
// ws layout: wpre[pix][16] floats; slot 15 = pad. OOB marked -1; invalid depth = 0.
__global__ __launch_bounds__(256) void weights_kernel(
    const float* __restrict__ depth,      // [B,1,H,W]
    const float* __restrict__ sn,         // [B,3,H,W]
    const float* __restrict__ guide,      // [B,H,W,25]
    const int*   __restrict__ sample_idx, // [15]
    float* __restrict__ wpre)             // [BHW][16]
{
    const int t   = threadIdx.x;
    const int s   = t & 15;              // sample slot
    const int lp  = t >> 4;              // local pixel (16 per block)
    const int pg  = blockIdx.x * 16 + lp;  // global pixel id
    const int b   = pg / HW;
    const int pix = pg - b * HW;
    const int y   = pix / W;
    const int x   = pix - y * W;

    const float* snb = sn + (size_t)b * 3 * HW;
    const float* db  = depth + (size_t)b * HW;

    float ww = 0.0f;   // slot 15 pad value
    if (s < SAMPLE_NUM) {
        // center_n per reference: RAW RESHAPE of [B,3,H,W] -> (B,H,W,3)
        int o = y * (W * 3) + x * 3;
        float cn0 = snb[o], cn1 = snb[o + 1], cn2 = snb[o + 2];

        int pp = sample_idx[s];
        int dy = pp / K_SIZE - PAD;
        int dx = pp - (pp / K_SIZE) * K_SIZE - PAD;
        int yy = y + dy, xx = x + dx;
        bool inb = (yy >= 0) && (yy < H) && (xx >= 0) && (xx < W);
        ww = -1.0f;                      // negative marks OOB (feature is zero-pad)
        if (inb) {
            ww = 0.0f;
            int noff = yy * W + xx;
            float d = db[noff];
            if (d > 0.0f && d < DEPTH_MAX) {
                float d0 = snb[noff]          - cn0;
                float d1 = snb[HW + noff]     - cn1;
                float d2 = snb[2 * HW + noff] - cn2;
                float diff = sqrtf(d0 * d0 + d1 * d1 + d2 * d2);
                ww = __expf(-0.5f * diff) * guide[((size_t)b * HW + pix) * 25 + pp];
            }
        }
    }
    wpre[(size_t)pg * 16 + s] = ww;
}

// ---------------- Kernel B: softmax + gather, one thread per (pixel, 4 channels) ----
constexpr int NGB = 8, CPGB = 4;       // 8 groups x 4 channels
constexpr int PB_BLOCKS = BHW / 256;   // 600 pixel blocks
constexpr int XCD_CHUNK = PB_BLOCKS / 8;  // 75

__global__ __launch_bounds__(256) void gather_kernel(
    const float* __restrict__ features,   // [B,C,H,W]
    const int*   __restrict__ sample_idx, // [15]
    const float* __restrict__ wpre,       // [BHW][16]
    float* __restrict__ out,              // [B,C,H,W]
    float* __restrict__ feat_out)         // [B,C,H,W]
{
    // XCD-chunked swizzle: each XCD gets a contiguous 75-pixel-block span
    // (60 image rows) for ALL 8 channel groups -> feature rows + weights L2-resident.
    int bid = blockIdx.x;                // 0..4799
    int xcd = bid & 7;
    int k   = bid >> 3;                  // 0..599
    int pb  = xcd * XCD_CHUNK + (k % XCD_CHUNK);
    int g   = k / XCD_CHUNK;             // 0..7

    const int t   = threadIdx.x;
    const int pg  = pb * 256 + t;        // global pixel id
    const int b   = pg / HW;
    const int pix = pg - b * HW;
    const int y   = pix / W;
    const int x   = pix - y * W;

    // 16 pre-weights as 4x float4 (64B per lane, dense across the wave)
    const float4* wp = (const float4*)(wpre + (size_t)pg * 16);
    float4 q0 = wp[0], q1 = wp[1], q2 = wp[2], q3 = wp[3];
    float v[16] = {q0.x, q0.y, q0.z, q0.w, q1.x, q1.y, q1.z, q1.w,
                   q2.x, q2.y, q2.z, q2.w, q3.x, q3.y, q3.z, q3.w};

    // offsets recomputed (VALU only; sample_idx is wave-uniform -> scalar loads)
    int offs[SAMPLE_NUM];
    #pragma unroll
    for (int s = 0; s < SAMPLE_NUM; ++s) {
        int pp = sample_idx[s];
        int dy = pp / K_SIZE - PAD;
        int dx = pp - (pp / K_SIZE) * K_SIZE - PAD;
        int yy = y + dy, xx = x + dx;
        bool inb = (yy >= 0) && (yy < H) && (xx >= 0) && (xx < W);
        offs[s] = inb ? (yy * W + xx) : pix;   // clamped; weight is zeroed below
    }

    // softmax over 15 (pre-softmax zeros participate; OOB -> accum weight 0)
    float m = 0.0f;
    #pragma unroll
    for (int s = 0; s < SAMPLE_NUM; ++s) m = fmaxf(m, v[s]);
    float e[SAMPLE_NUM];
    float sum = 0.0f;
    #pragma unroll
    for (int s = 0; s < SAMPLE_NUM; ++s) {
        e[s] = __expf(fmaxf(v[s], 0.0f) - m);
        sum += e[s];
    }
    float inv = 1.0f / sum;
    float wv[SAMPLE_NUM];
    #pragma unroll
    for (int s = 0; s < SAMPLE_NUM; ++s)
        wv[s] = (v[s] < 0.0f) ? 0.0f : e[s] * inv;

    const float* fb  = features + (size_t)b * C * HW;
    float*       ob  = out      + (size_t)b * C * HW;
    float*       fob = feat_out + (size_t)b * C * HW;
    const int c0 = g * CPGB;

    float acc[CPGB];
    #pragma unroll
    for (int cc = 0; cc < CPGB; ++cc) acc[cc] = 0.0f;

    #pragma unroll
    for (int s = 0; s < SAMPLE_NUM; ++s) {
        const float* fo = fb + offs[s];
        float wgt = wv[s];
        #pragma unroll
        for (int cc = 0; cc < CPGB; ++cc)
            acc[cc] = fmaf(wgt, fo[(size_t)(c0 + cc) * HW], acc[cc]);
    }

    #pragma unroll
    for (int cc = 0; cc < CPGB; ++cc) {
        size_t idx = (size_t)(c0 + cc) * HW + pix;
        ob[idx]  = acc[cc];      // weighted sample output
        fob[idx] = fb[idx];      // features passthrough (output 1)
    }
}

// ---------------- Fallback (round-3 fused kernel) if ws is too small ----------------
__global__ __launch_bounds__(256) void fused_fallback(
    const float* __restrict__ depth, const float* __restrict__ sn,
    const float* __restrict__ features, const float* __restrict__ guide,
    const int* __restrict__ sample_idx, float* __restrict__ out,
    float* __restrict__ feat_out)
{
    constexpr int PIX_BLOCKS = BHW / 256;
    int pb = blockIdx.x % PIX_BLOCKS;
    int g  = blockIdx.x / PIX_BLOCKS;
    int n  = pb * 256 + threadIdx.x;
    int b = n / HW, pix = n - b * HW, y = pix / W, x = pix - y * W;
    const float* snb = sn + (size_t)b * 3 * HW;
    const float* db  = depth + (size_t)b * HW;
    const float* gb  = guide + ((size_t)b * HW + pix) * 25;
    int o = y * (W * 3) + x * 3;
    float cn0 = snb[o], cn1 = snb[o + 1], cn2 = snb[o + 2];
    float w[SAMPLE_NUM]; int offs[SAMPLE_NUM]; bool inbv[SAMPLE_NUM];
    float m = 0.0f;
    #pragma unroll
    for (int s = 0; s < SAMPLE_NUM; ++s) {
        int pp = sample_idx[s];
        int dy = pp / K_SIZE - PAD, dx = pp - (pp / K_SIZE) * K_SIZE - PAD;
        int yy = y + dy, xx = x + dx;
        bool inb = (yy >= 0) && (yy < H) && (xx >= 0) && (xx < W);
        inbv[s] = inb;
        int noff = inb ? (yy * W + xx) : pix;
        offs[s] = noff;
        float ww = 0.0f;
        if (inb) {
            float d = db[noff];
            if (d > 0.0f && d < DEPTH_MAX) {
                float d0 = snb[noff] - cn0, d1 = snb[HW + noff] - cn1, d2 = snb[2 * HW + noff] - cn2;
                ww = __expf(-0.5f * sqrtf(d0 * d0 + d1 * d1 + d2 * d2)) * gb[pp];
            }
        }
        w[s] = ww; m = fmaxf(m, ww);
    }
    float sum = 0.0f;
    #pragma unroll
    for (int s = 0; s < SAMPLE_NUM; ++s) { w[s] = __expf(w[s] - m); sum += w[s]; }
    float inv = 1.0f / sum;
    #pragma unroll
    for (int s = 0; s < SAMPLE_NUM; ++s) w[s] = inbv[s] ? (w[s] * inv) : 0.0f;
    const float* fb = features + (size_t)b * C * HW;
    float* ob = out + (size_t)b * C * HW;
    float* fob = feat_out + (size_t)b * C * HW;
    int c0 = g * 8;
    #pragma unroll
    for (int cc = 0; cc < 8; ++cc) {
        const float* fc = fb + (c0 + cc) * HW;
        float acc = 0.0f;
        #pragma unroll
        for (int s = 0; s < SAMPLE_NUM; ++s) acc += w[s] * fc[offs[s]];
        ob[(size_t)(c0 + cc) * HW + pix] = acc;
        fob[(size_t)(c0 + cc) * HW + pix] = fc[pix];
    }
}

extern "C" void kernel_launch(void* const* d_in, const int* in_sizes, int n_in,
                              void* d_out, int out_size, void* d_ws, size_t ws_size,
                              hipStream_t stream) {
    const float* depth      = (const float*)d_in[0];
    const float* sn         = (const float*)d_in[1];
    const float* features   = (const float*)d_in[2];
    const float* guide      = (const float*)d_in[3];
    const int*   sample_idx = (const int*)d_in[4];

    float* out      = (float*)d_out;                      // [B,C,H,W]
    float* feat_out = (float*)d_out + (size_t)B * C * HW; // [B,C,H,W]

    if (ws_size >= WS_NEED) {
        float* wpre = (float*)d_ws;
        weights_kernel<<<BHW / 16, 256, 0, stream>>>(depth, sn, guide, sample_idx, wpre);
        gather_kernel<<<PB_BLOCKS * NGB, 256, 0, stream>>>(features, sample_idx, wpre, out, feat_out);
    } else {
        fused_fallback<<<(BHW / 256) * 4, 256, 0, stream>>>(
            depth, sn, features, guide, sample_idx, out, feat_out);
    }
}